// Round 1
// baseline (1343.964 us; speedup 1.0000x reference)
//
#include <hip/hip_runtime.h>
#include <math.h>

// Problem constants
#define NB 1024      // batch
#define LL 128       // max length
#define HH 512       // hidden
#define OO 32000     // vocab

// ---------------------------------------------------------------------------
// Tiled fp32 SGEMM:  C[m][n] = act( sum_k A[m][k]*B[n][k] + bias[n] )
// A: [M,K] row-major, B: [N,K] row-major (i.e. C = A @ B^T), K%16==0, M,N%64==0
// ACT: 0 = none, 1 = relu
// ---------------------------------------------------------------------------
template<int ACT>
__global__ __launch_bounds__(256) void sgemm_bias(
    const float* __restrict__ A, const float* __restrict__ B,
    const float* __restrict__ bias, float* __restrict__ C,
    int M, int Ncols, int K)
{
    const int BM = 64, BN = 64, BK = 16;
    __shared__ float As[BK][BM];
    __shared__ float Bs[BK][BN];

    const int bm = blockIdx.y * BM;
    const int bn = blockIdx.x * BN;
    const int tid = threadIdx.x;          // 256 threads
    const int tr = tid / 16;              // 0..15
    const int tc = tid % 16;              // 0..15

    const int lr = tid / 4;               // 0..63 (row within tile)
    const int lk = (tid % 4) * 4;         // 0,4,8,12 (k offset)

    float acc[4][4] = {};

    for (int k0 = 0; k0 < K; k0 += BK) {
        float4 a4 = *(const float4*)&A[(size_t)(bm + lr) * K + k0 + lk];
        float4 b4 = *(const float4*)&B[(size_t)(bn + lr) * K + k0 + lk];
        __syncthreads();   // previous iteration's reads done before overwrite
        As[lk + 0][lr] = a4.x; As[lk + 1][lr] = a4.y;
        As[lk + 2][lr] = a4.z; As[lk + 3][lr] = a4.w;
        Bs[lk + 0][lr] = b4.x; Bs[lk + 1][lr] = b4.y;
        Bs[lk + 2][lr] = b4.z; Bs[lk + 3][lr] = b4.w;
        __syncthreads();
        #pragma unroll
        for (int k = 0; k < BK; ++k) {
            float4 av = *(const float4*)&As[k][tr * 4];
            float4 bv = *(const float4*)&Bs[k][tc * 4];
            float a[4] = {av.x, av.y, av.z, av.w};
            float b[4] = {bv.x, bv.y, bv.z, bv.w};
            #pragma unroll
            for (int i = 0; i < 4; ++i)
                #pragma unroll
                for (int j = 0; j < 4; ++j)
                    acc[i][j] += a[i] * b[j];
        }
    }

    #pragma unroll
    for (int i = 0; i < 4; ++i) {
        int row = bm + tr * 4 + i;
        #pragma unroll
        for (int j = 0; j < 4; ++j) {
            int col = bn + tc * 4 + j;
            float v = acc[i][j] + bias[col];
            if (ACT == 1) v = fmaxf(v, 0.0f);
            C[(size_t)row * Ncols + col] = v;
        }
    }
}

// ---------------------------------------------------------------------------
// Gather embedding row + build concatenated inputs
// cat_eh = [embedded | hidden], cat_ea = [embedded | (attn_applied later)]
// ---------------------------------------------------------------------------
__global__ void gather_embed(const int* __restrict__ ids,
                             const float* __restrict__ emb,
                             const float* __restrict__ hidden,
                             float* __restrict__ cat_eh,
                             float* __restrict__ cat_ea)
{
    int idx = blockIdx.x * blockDim.x + threadIdx.x;   // N*H
    int n = idx >> 9, k = idx & 511;
    float e = emb[(size_t)ids[n] * HH + k];
    cat_eh[(size_t)n * 1024 + k] = e;
    cat_ea[(size_t)n * 1024 + k] = e;
    cat_eh[(size_t)n * 1024 + 512 + k] = hidden[idx];
}

// ---------------------------------------------------------------------------
// Softmax over L=128, one block (128 threads) per row
// ---------------------------------------------------------------------------
__global__ void softmax128(const float* __restrict__ logits,
                           float* __restrict__ w_out)
{
    int n = blockIdx.x;
    int t = threadIdx.x;   // 128
    __shared__ float buf[128];
    float v = logits[(size_t)n * LL + t];
    buf[t] = v;
    __syncthreads();
    for (int s = 64; s > 0; s >>= 1) {
        if (t < s) buf[t] = fmaxf(buf[t], buf[t + s]);
        __syncthreads();
    }
    float m = buf[0];
    __syncthreads();
    float e = expf(v - m);
    buf[t] = e;
    __syncthreads();
    for (int s = 64; s > 0; s >>= 1) {
        if (t < s) buf[t] += buf[t + s];
        __syncthreads();
    }
    float s = buf[0];
    w_out[(size_t)n * LL + t] = e / s;
}

// ---------------------------------------------------------------------------
// attn_applied[n][h] = sum_l w[n][l] * enc[n][l][h] * mask[n][l][h]
// one block per n, 256 threads, float2 per thread
// ---------------------------------------------------------------------------
__global__ __launch_bounds__(256) void attn_apply(
    const float* __restrict__ w, const float* __restrict__ enc,
    const float* __restrict__ mask, float* __restrict__ cat_ea)
{
    int n = blockIdx.x;
    int t = threadIdx.x;   // 256
    __shared__ float wl[LL];
    if (t < LL) wl[t] = w[(size_t)n * LL + t];
    __syncthreads();
    const float2* ep = (const float2*)(enc + (size_t)n * LL * HH);
    const float2* mp = (const float2*)(mask + (size_t)n * LL * HH);
    float2 acc = {0.f, 0.f};
    #pragma unroll 4
    for (int l = 0; l < LL; ++l) {
        float wv = wl[l];
        float2 e = ep[l * (HH / 2) + t];
        float2 m = mp[l * (HH / 2) + t];
        acc.x += wv * e.x * m.x;
        acc.y += wv * e.y * m.y;
    }
    ((float2*)(cat_ea + (size_t)n * 1024 + 512))[t] = acc;
}

// ---------------------------------------------------------------------------
// GRU elementwise:  r,z,n gates -> h_new
// ---------------------------------------------------------------------------
__global__ void gru_elem(const float* __restrict__ gx,
                         const float* __restrict__ gh,
                         const float* __restrict__ hidden,
                         float* __restrict__ h_new)
{
    int idx = blockIdx.x * blockDim.x + threadIdx.x;   // N*H
    int n = idx >> 9, h = idx & 511;
    const float* gxr = gx + (size_t)n * 1536;
    const float* ghr = gh + (size_t)n * 1536;
    float r = 1.f / (1.f + expf(-(gxr[h] + ghr[h])));
    float z = 1.f / (1.f + expf(-(gxr[512 + h] + ghr[512 + h])));
    float nn = tanhf(gxr[1024 + h] + r * ghr[1024 + h]);
    float hp = hidden[idx];
    h_new[idx] = (1.f - z) * nn + z * hp;
}

// ---------------------------------------------------------------------------
// In-place log_softmax per row of length O, one block (256 threads) per row
// ---------------------------------------------------------------------------
__global__ __launch_bounds__(256) void logsoftmax_rows(float* __restrict__ out)
{
    int n = blockIdx.x;
    int t = threadIdx.x;   // 256
    float* row = out + (size_t)n * OO;
    float m = -INFINITY, s = 0.f;
    for (int o = t; o < OO; o += 256) {
        float v = row[o];
        if (v > m) { s = s * expf(m - v) + 1.f; m = v; }
        else       { s += expf(v - m); }
    }
    __shared__ float ms[256], ss[256];
    ms[t] = m; ss[t] = s;
    __syncthreads();
    for (int st = 128; st > 0; st >>= 1) {
        if (t < st) {
            float m2 = ms[t + st], s2 = ss[t + st];
            float mm = fmaxf(ms[t], m2);
            ss[t] = ss[t] * expf(ms[t] - mm) + s2 * expf(m2 - mm);
            ms[t] = mm;
        }
        __syncthreads();
    }
    float lse = ms[0] + logf(ss[0]);
    for (int o = t; o < OO; o += 256) row[o] -= lse;
}

// ---------------------------------------------------------------------------
extern "C" void kernel_launch(void* const* d_in, const int* in_sizes, int n_in,
                              void* d_out, int out_size, void* d_ws, size_t ws_size,
                              hipStream_t stream)
{
    const int*   input_ids = (const int*)  d_in[0];
    const float* hidden    = (const float*)d_in[1];
    const float* enc       = (const float*)d_in[2];
    const float* mask      = (const float*)d_in[3];
    const float* emb       = (const float*)d_in[4];
    const float* attn_W    = (const float*)d_in[5];
    const float* attn_b    = (const float*)d_in[6];
    const float* comb_W    = (const float*)d_in[7];
    const float* comb_b    = (const float*)d_in[8];
    const float* W_ih      = (const float*)d_in[9];
    const float* W_hh      = (const float*)d_in[10];
    const float* b_ih      = (const float*)d_in[11];
    const float* b_hh      = (const float*)d_in[12];
    const float* out_W     = (const float*)d_in[13];
    const float* out_b     = (const float*)d_in[14];

    float* out      = (float*)d_out;
    float* out_logp = out;                                  // [N,O]
    float* out_h    = out + (size_t)NB * OO;                // [N,H]
    float* out_w    = out + (size_t)NB * OO + NB * HH;      // [N,L]

    float* ws          = (float*)d_ws;
    float* cat_eh      = ws;                    // N*2H = 1048576
    float* cat_ea      = ws + 1048576;          // N*2H = 1048576
    float* attn_logits = ws + 2097152;          // N*L  = 131072
    float* xbuf        = ws + 2228224;          // N*H  = 524288
    float* gx          = ws + 2752512;          // N*3H = 1572864
    float* gh          = ws + 4325376;          // N*3H = 1572864
    // total 5898240 floats = 23.6 MB

    // 1. gather embedding + build concatenations
    gather_embed<<<(NB * HH) / 256, 256, 0, stream>>>(input_ids, emb, hidden,
                                                      cat_eh, cat_ea);
    // 2. attention logits: [N,2H] @ [L,2H]^T + b
    sgemm_bias<0><<<dim3(LL / 64, NB / 64), 256, 0, stream>>>(
        cat_eh, attn_W, attn_b, attn_logits, NB, LL, 2 * HH);
    // 3. softmax over L -> attn_weights (output 2)
    softmax128<<<NB, 128, 0, stream>>>(attn_logits, out_w);
    // 4. weighted sum over masked encoder outputs -> cat_ea second half
    attn_apply<<<NB, 256, 0, stream>>>(out_w, enc, mask, cat_ea);
    // 5. combine + relu: [N,2H] @ [H,2H]^T + b
    sgemm_bias<1><<<dim3(HH / 64, NB / 64), 256, 0, stream>>>(
        cat_ea, comb_W, comb_b, xbuf, NB, HH, 2 * HH);
    // 6/7. GRU input & hidden projections: [N,H] @ [3H,H]^T + b
    sgemm_bias<0><<<dim3((3 * HH) / 64, NB / 64), 256, 0, stream>>>(
        xbuf, W_ih, b_ih, gx, NB, 3 * HH, HH);
    sgemm_bias<0><<<dim3((3 * HH) / 64, NB / 64), 256, 0, stream>>>(
        hidden, W_hh, b_hh, gh, NB, 3 * HH, HH);
    // 8. GRU gates -> h_new (output 1)
    gru_elem<<<(NB * HH) / 256, 256, 0, stream>>>(gx, gh, hidden, out_h);
    // 9. output projection: [N,H] @ [O,H]^T + b -> logits in d_out
    sgemm_bias<0><<<dim3(OO / 64, NB / 64), 256, 0, stream>>>(
        out_h, out_W, out_b, out_logp, NB, OO, HH);
    // 10. in-place log_softmax
    logsoftmax_rows<<<NB, 256, 0, stream>>>(out_logp);
}